// Round 12
// baseline (215.933 us; speedup 1.0000x reference)
//
#include <hip/hip_runtime.h>
#include <hip/hip_bf16.h>
#include <cstdio>

typedef float f32x4 __attribute__((ext_vector_type(4)));
typedef __bf16 bf16x8 __attribute__((ext_vector_type(8)));

static constexpr int Bn = 8, Nn = 2048, Dn = 512, Hn = 512;

__device__ __forceinline__ unsigned short f2bf(float x) {
    union { float f; unsigned int u; } v; v.f = x;
    unsigned int r = (v.u + 0x7FFFu + ((v.u >> 16) & 1u)) >> 16;
    return (unsigned short)r;
}
__device__ __forceinline__ float bf2f(unsigned short h) {
    union { unsigned int u; float f; } v; v.u = ((unsigned int)h) << 16;
    return v.f;
}

__device__ __forceinline__ void gload_lds16(const unsigned short* g, unsigned short* l) {
    __builtin_amdgcn_global_load_lds(
        (const __attribute__((address_space(1))) void*)g,
        (__attribute__((address_space(3))) void*)l,
        16, 0, 0);
}

__device__ __forceinline__ int xcd_swizzle(int lin, int nwg) {
    return (lin & 7) * (nwg >> 3) + (lin >> 3);   // all grids %8==0
}

// ---------------- cast x (f32 -> bf16), flat ----------------
__global__ void cast_x_kernel(const float* __restrict__ x, unsigned short* __restrict__ xb, int n) {
    int i = (blockIdx.x * blockDim.x + threadIdx.x) * 8;
    if (i >= n) return;
    float4 a = *(const float4*)(x + i);
    float4 b = *(const float4*)(x + i + 4);
    unsigned short tmp[8] = {f2bf(a.x), f2bf(a.y), f2bf(a.z), f2bf(a.w),
                             f2bf(b.x), f2bf(b.y), f2bf(b.z), f2bf(b.w)};
    *(uint4*)(xb + i) = *(const uint4*)tmp;
}

// ---- weight transpose+cast: z=0 -> Wq, z=1 -> Wk; f32 [D][H] -> bf16 [H][D] ----
__global__ __launch_bounds__(256) void transpose_cast_w(
    const float* __restrict__ Wq, const float* __restrict__ Wk,
    unsigned short* __restrict__ out)
{
    __shared__ float tile[64][65];
    const int z = blockIdx.z;
    const float* inb = z ? Wk : Wq;
    unsigned short* outb = out + (size_t)z * Hn * Dn;
    const int r0 = blockIdx.y * 64, c0 = blockIdx.x * 64;
    const int tx = threadIdx.x & 63, ty = threadIdx.x >> 6;
#pragma unroll
    for (int p = 0; p < 64; p += 4) {
        const int r = p + ty;
        tile[r][tx] = inb[(size_t)(r0 + r) * Hn + c0 + tx];
    }
    __syncthreads();
#pragma unroll
    for (int p = 0; p < 64; p += 4) {
        const int oc = p + ty;
        outb[(size_t)(c0 + oc) * Dn + r0 + tx] = f2bf(tile[tx][oc]);
    }
}

// ---- xsT[b][d][j] = bf16(xb[b][j][d] / s[b][j]); s computed in-kernel from partials ----
__global__ __launch_bounds__(256) void transpose_scale_bf16(
    const unsigned short* __restrict__ xb, unsigned short* __restrict__ out,
    const float* __restrict__ s_part, int nblk)
{
    __shared__ unsigned short tile[64][65];
    __shared__ float ss[64];
    const int z = blockIdx.z;
    const unsigned short* inb = xb + (size_t)z * Nn * Dn;
    unsigned short* ob = out + (size_t)z * Nn * Dn;
    const int j0 = blockIdx.y * 64, d0 = blockIdx.x * 64;
    const int tx = threadIdx.x & 63, ty = threadIdx.x >> 6;
    if (threadIdx.x < 64) {
        float acc = 0.f;
        for (int p = 0; p < nblk; ++p)
            acc += s_part[((size_t)z * nblk + p) * Nn + j0 + threadIdx.x];
        ss[threadIdx.x] = acc;
    }
#pragma unroll
    for (int p = 0; p < 64; p += 4) {
        const int r = p + ty;
        tile[r][tx] = inb[(size_t)(j0 + r) * Dn + d0 + tx];
    }
    __syncthreads();
    const float sv = ss[tx];
#pragma unroll
    for (int p = 0; p < 64; p += 4) {
        const int oc = p + ty;
        ob[(size_t)(d0 + oc) * Nn + j0 + tx] = f2bf(bf2f(tile[tx][oc]) / sv);
    }
}

// ===== 256x128 single-buffer 2-barrier GEMM, 4 waves, wave-tile 128x64 — PROJ shape =====
// (R10-proven winner for M=16384,N=1024,K=512.)
__global__ __launch_bounds__(256, 2) void gemw3(
    const unsigned short* __restrict__ A, int lda,
    const unsigned short* __restrict__ Bt, int ldb,
    unsigned short* __restrict__ Cp,
    const float* __restrict__ bias, const float* __restrict__ bias2, int bsplit,
    int M, int N, int K, int gx, int gy)
{
    __shared__ unsigned short As[256 * 64];   // 32 KB
    __shared__ unsigned short Bs[128 * 64];   // 16 KB

    const int lin = xcd_swizzle(blockIdx.x, gridDim.x);
    const int by = lin / gx;
    const int bx = lin - by * gx;

    const int i0 = by * 256, j0 = bx * 128;

    const int t = threadIdx.x;
    const int lane = t & 63;
    const int w = t >> 6;              // 0..3
    const int wm = w >> 1, wn = w & 1; // wave-tile 128 x 64
    const int l15 = lane & 15, g = lane >> 4;

    f32x4 acc[8][4];
    const f32x4 zero4 = {0.f, 0.f, 0.f, 0.f};
#pragma unroll
    for (int mf = 0; mf < 8; ++mf)
#pragma unroll
        for (int nf = 0; nf < 4; ++nf) acc[mf][nf] = zero4;

    const int lrow = lane >> 3;
    const int gch = (lane & 7) ^ lrow;   // pre-swizzled source chunk (involution)

    for (int kt = 0; kt < K; kt += 64) {
#pragma unroll
        for (int i = 0; i < 8; ++i) {
            const int r = w * 64 + i * 8 + lrow;
            gload_lds16(A + (size_t)(i0 + r) * lda + kt + gch * 8,
                        As + (w * 64 + i * 8) * 64);
        }
#pragma unroll
        for (int i = 0; i < 4; ++i) {
            const int r = w * 32 + i * 8 + lrow;
            gload_lds16(Bt + (size_t)(j0 + r) * ldb + kt + gch * 8,
                        Bs + (w * 32 + i * 8) * 64);
        }
        __syncthreads();
#pragma unroll
        for (int kk = 0; kk < 64; kk += 32) {
            const int sl0 = (kk >> 3) + g;
            bf16x8 af[8], bfr[4];
#pragma unroll
            for (int mf = 0; mf < 8; ++mf) {
                const int row = wm * 128 + mf * 16 + l15;
                af[mf] = *(const bf16x8*)(As + row * 64 + ((sl0 ^ (row & 7)) * 8));
            }
#pragma unroll
            for (int nf = 0; nf < 4; ++nf) {
                const int row = wn * 64 + nf * 16 + l15;
                bfr[nf] = *(const bf16x8*)(Bs + row * 64 + ((sl0 ^ (row & 7)) * 8));
            }
#pragma unroll
            for (int mf = 0; mf < 8; ++mf)
#pragma unroll
                for (int nf = 0; nf < 4; ++nf)
                    acc[mf][nf] = __builtin_amdgcn_mfma_f32_16x16x32_bf16(af[mf], bfr[nf], acc[mf][nf], 0, 0, 0);
        }
        __syncthreads();
    }

    const int col0 = j0 + wn * 64 + l15;
    float bv[4];
#pragma unroll
    for (int nf = 0; nf < 4; ++nf) {
        const int col = col0 + nf * 16;
        bv[nf] = (col < bsplit) ? bias[col] : bias2[col - bsplit];
    }
#pragma unroll
    for (int mf = 0; mf < 8; ++mf) {
        const int rb = i0 + wm * 128 + mf * 16 + g * 4;
#pragma unroll
        for (int r = 0; r < 4; ++r) {
            unsigned short* Crow = Cp + (size_t)(rb + r) * N + col0;
#pragma unroll
            for (int nf = 0; nf < 4; ++nf)
                Crow[nf * 16] = f2bf(acc[mf][nf][r] + bv[nf]);
        }
    }
}

// ===== 128x128 GEMM, A fragments DIRECT FROM GLOBAL (L2-resident), B via LDS =====
// Mechanism: A-panels are L2-resident (q reused x16 blocks; expE row-panels x4).
// Per-lane global dwordx4 loads of A frags (lanes (l15,g) form 64B segments);
// B keeps the R8-proven single-buffer gload_lds + chunk^(row&7) swizzle + 2x
// __syncthreads. LDS drops 33->17 KB -> 8 blocks/CU resident (stall hiding).
// MODE 1: C bf16=exp(acc) + col-sum partials | MODE 2: C f32
template<int MODE>
__global__ __launch_bounds__(256, 2) void gemm_ag(
    const unsigned short* __restrict__ A, long long sA, int lda,
    const unsigned short* __restrict__ Bt, long long sB, int ldb,
    void* __restrict__ Cp, long long sC,
    float* __restrict__ s_part,
    int M, int N, int K, int gx, int gy)
{
    __shared__ unsigned short Bs[128 * 64];   // 16 KB
    __shared__ float s_red[256];              // 1 KB

    const int lin = xcd_swizzle(blockIdx.x, gridDim.x);
    const int bz = lin / (gx * gy);
    const int rem = lin - bz * gx * gy;
    const int by = rem / gx;
    const int bx = rem - by * gx;

    const unsigned short* Ab = A + (size_t)bz * sA;
    const unsigned short* Bb = Bt + (size_t)bz * sB;
    const int i0 = by * 128, j0 = bx * 128;

    const int t = threadIdx.x;
    const int lane = t & 63;
    const int wave = t >> 6;
    const int wr = wave >> 1, wc = wave & 1;
    const int l15 = lane & 15, g = lane >> 4;

    f32x4 acc[4][4];
    const f32x4 zero4 = {0.f, 0.f, 0.f, 0.f};
#pragma unroll
    for (int mi = 0; mi < 4; ++mi)
#pragma unroll
        for (int ni = 0; ni < 4; ++ni) acc[mi][ni] = zero4;

    // per-lane A row base pointers (frag row = i0 + wr*64 + mi*16 + l15, k-lane g*8)
    const unsigned short* Arow[4];
#pragma unroll
    for (int mi = 0; mi < 4; ++mi)
        Arow[mi] = Ab + (size_t)(i0 + wr * 64 + mi * 16 + l15) * lda + g * 8;

    const int rbase = wave * 32;
    const int lrow = lane >> 3;
    const int gch = (lane & 7) ^ lrow;

    for (int kt = 0; kt < K; kt += 64) {
        // stage B only: 4 gload_lds per wave
#pragma unroll
        for (int i = 0; i < 4; ++i) {
            const int r = rbase + i * 8 + lrow;
            gload_lds16(Bb + (size_t)(j0 + r) * ldb + kt + gch * 8, Bs + (rbase + i * 8) * 64);
        }
        __syncthreads();
#pragma unroll
        for (int kk = 0; kk < 64; kk += 32) {
            const int sl0 = (kk >> 3) + g;
            bf16x8 af[4], bfr[4];
#pragma unroll
            for (int mi = 0; mi < 4; ++mi)
                af[mi] = *(const bf16x8*)(Arow[mi] + kt + kk);     // global dwordx4 (L2)
#pragma unroll
            for (int ni = 0; ni < 4; ++ni) {
                const int row = wc * 64 + ni * 16 + l15;
                bfr[ni] = *(const bf16x8*)(Bs + row * 64 + ((sl0 ^ (row & 7)) * 8));
            }
#pragma unroll
            for (int mi = 0; mi < 4; ++mi)
#pragma unroll
                for (int ni = 0; ni < 4; ++ni)
                    acc[mi][ni] = __builtin_amdgcn_mfma_f32_16x16x32_bf16(af[mi], bfr[ni], acc[mi][ni], 0, 0, 0);
        }
        __syncthreads();
    }

    const int col0 = j0 + wc * 64 + l15;
    if (MODE == 1) {
        unsigned short* C = (unsigned short*)Cp + (size_t)bz * sC;
        float cs[4] = {0.f, 0.f, 0.f, 0.f};
#pragma unroll
        for (int mi = 0; mi < 4; ++mi) {
            const int rb = i0 + wr * 64 + mi * 16 + g * 4;
#pragma unroll
            for (int r = 0; r < 4; ++r) {
                unsigned short* Crow = C + (size_t)(rb + r) * N + col0;
#pragma unroll
                for (int ni = 0; ni < 4; ++ni) {
                    const float e = __expf(acc[mi][ni][r]);
                    const unsigned short h = f2bf(e);
                    Crow[ni * 16] = h;
                    cs[ni] += bf2f(h);   // sum rounded value: num/denom consistency
                }
            }
        }
#pragma unroll
        for (int ni = 0; ni < 4; ++ni) {
            cs[ni] += __shfl_xor(cs[ni], 16);
            cs[ni] += __shfl_xor(cs[ni], 32);
        }
        if (g == 0) {
#pragma unroll
            for (int ni = 0; ni < 4; ++ni)
                s_red[wr * 128 + wc * 64 + ni * 16 + l15] = cs[ni];
        }
        __syncthreads();
        if (t < 128) {
            const float sp = s_red[t] + s_red[128 + t];
            s_part[((size_t)bz * gy + by) * Nn + j0 + t] = sp;
        }
    } else {
        float* C = (float*)Cp + (size_t)bz * sC;
#pragma unroll
        for (int mi = 0; mi < 4; ++mi) {
            const int rb = i0 + wr * 64 + mi * 16 + g * 4;
#pragma unroll
            for (int r = 0; r < 4; ++r) {
                float* Crow = C + (size_t)(rb + r) * N + col0;
#pragma unroll
                for (int ni = 0; ni < 4; ++ni)
                    Crow[ni * 16] = acc[mi][ni][r];
            }
        }
    }
}

extern "C" void kernel_launch(void* const* d_in, const int* in_sizes, int n_in,
                              void* d_out, int out_size, void* d_ws, size_t ws_size,
                              hipStream_t stream) {
    const float* x  = (const float*)d_in[0];
    const float* Wq = (const float*)d_in[1];
    const float* bq = (const float*)d_in[2];
    const float* Wk = (const float*)d_in[3];
    const float* bk = (const float*)d_in[4];
    float* out = (float*)d_out;

    // ws layout (116 MB): xsT reuses qk's space (qk dead after energy GEMM)
    char* ws = (char*)d_ws;
    unsigned short* xb    = (unsigned short*)(ws);                               // 0..16 MB
    unsigned short* qk    = (unsigned short*)(ws + (16ull << 20));               // 16..48 MB [16384][1024]
    unsigned short* xsT   = (unsigned short*)(ws + (16ull << 20));               // reuse (written step 5)
    unsigned short* WqkT  = (unsigned short*)(ws + (48ull << 20));               // 48..49 MB [1024][512]
    float*          s_prt = (float*)(ws + (49ull << 20));                        // 49..51 MB
    unsigned short* expE  = (unsigned short*)(ws + (52ull << 20));               // 52..116 MB
    if (ws_size < (116ull << 20)) {
        fprintf(stderr, "WS TOO SMALL: have %zu need %llu\n", ws_size, (116ull << 20));
    }

    // 1) xb = bf16(x)
    cast_x_kernel<<<dim3((Bn * Nn * Dn) / (8 * 256)), 256, 0, stream>>>(x, xb, Bn * Nn * Dn);
    // 2) WqkT = bf16([Wq; Wk]^T)
    transpose_cast_w<<<dim3(Hn / 64, Dn / 64, 2), 256, 0, stream>>>(Wq, Wk, WqkT);
    // 3) qk = xb @ [Wq|Wk] + [bq|bk]   (M=16384, N=1024, K=512) — gemw3, 8 x 64 = 512 blocks
    {
        const int gx = (2 * Hn) / 128, gy = (Bn * Nn) / 256;
        gemw3<<<dim3(gx * gy), 256, 0, stream>>>(
            xb, Dn, WqkT, Dn, qk, bq, bk, Hn, Bn * Nn, 2 * Hn, Dn, gx, gy);
    }
    // 4) expE = exp(q @ k^T) + col-sum partials (per batch; M=N=2048, K=512) — 16x16x8 = 2048 blocks
    {
        const int gx = Nn / 128, gy = Nn / 128;
        gemm_ag<1><<<dim3(gx * gy * Bn), 256, 0, stream>>>(
            qk, (long long)Nn * 2 * Hn, 2 * Hn,               // q = qk[:, 0:512]
            qk + Hn, (long long)Nn * 2 * Hn, 2 * Hn,          // k = qk[:, 512:1024]
            expE, (long long)Nn * Nn, s_prt,
            Nn, Nn, Hn, gx, gy);
    }
    // 5) xsT[b][d][j] = bf16(xb[b][j][d] / s[b][j])  (s summed in-kernel from 16 partials)
    transpose_scale_bf16<<<dim3(Dn / 64, Nn / 64, Bn), 256, 0, stream>>>(xb, xsT, s_prt, Nn / 128);
    // 6) out = expE @ xsT^T   (per batch; M=2048, N=512, K=2048) — 4 x 16 x 8 = 512 blocks
    {
        const int gx = Dn / 128, gy = Nn / 128;
        gemm_ag<2><<<dim3(gx * gy * Bn), 256, 0, stream>>>(
            expE, (long long)Nn * Nn, Nn, xsT, (long long)Dn * Nn, Nn,
            out, (long long)Nn * Dn, nullptr,
            Nn, Dn, Nn, gx, gy);
    }
}

// Round 13
// 136.353 us; speedup vs baseline: 1.5836x; 1.5836x over previous
//
#include <hip/hip_runtime.h>
#include <hip/hip_bf16.h>
#include <cstdio>

typedef float f32x4 __attribute__((ext_vector_type(4)));
typedef __bf16 bf16x8 __attribute__((ext_vector_type(8)));

static constexpr int Bn = 8, Nn = 2048, Dn = 512, Hn = 512;

__device__ __forceinline__ unsigned short f2bf(float x) {
    union { float f; unsigned int u; } v; v.f = x;
    unsigned int r = (v.u + 0x7FFFu + ((v.u >> 16) & 1u)) >> 16;
    return (unsigned short)r;
}
__device__ __forceinline__ float bf2f(unsigned short h) {
    union { unsigned int u; float f; } v; v.u = ((unsigned int)h) << 16;
    return v.f;
}

__device__ __forceinline__ void gload_lds16(const unsigned short* g, unsigned short* l) {
    __builtin_amdgcn_global_load_lds(
        (const __attribute__((address_space(1))) void*)g,
        (__attribute__((address_space(3))) void*)l,
        16, 0, 0);
}

__device__ __forceinline__ int xcd_swizzle(int lin, int nwg) {
    return (lin & 7) * (nwg >> 3) + (lin >> 3);   // all grids %8==0
}

// ---------------- cast x (f32 -> bf16), flat ----------------
__global__ void cast_x_kernel(const float* __restrict__ x, unsigned short* __restrict__ xb, int n) {
    int i = (blockIdx.x * blockDim.x + threadIdx.x) * 8;
    if (i >= n) return;
    float4 a = *(const float4*)(x + i);
    float4 b = *(const float4*)(x + i + 4);
    unsigned short tmp[8] = {f2bf(a.x), f2bf(a.y), f2bf(a.z), f2bf(a.w),
                             f2bf(b.x), f2bf(b.y), f2bf(b.z), f2bf(b.w)};
    *(uint4*)(xb + i) = *(const uint4*)tmp;
}

// ---- weight transpose+cast: z=0 -> Wq, z=1 -> Wk; f32 [D][H] -> bf16 [H][D] ----
__global__ __launch_bounds__(256) void transpose_cast_w(
    const float* __restrict__ Wq, const float* __restrict__ Wk,
    unsigned short* __restrict__ out)
{
    __shared__ float tile[64][65];
    const int z = blockIdx.z;
    const float* inb = z ? Wk : Wq;
    unsigned short* outb = out + (size_t)z * Hn * Dn;
    const int r0 = blockIdx.y * 64, c0 = blockIdx.x * 64;
    const int tx = threadIdx.x & 63, ty = threadIdx.x >> 6;
#pragma unroll
    for (int p = 0; p < 64; p += 4) {
        const int r = p + ty;
        tile[r][tx] = inb[(size_t)(r0 + r) * Hn + c0 + tx];
    }
    __syncthreads();
#pragma unroll
    for (int p = 0; p < 64; p += 4) {
        const int oc = p + ty;
        outb[(size_t)(c0 + oc) * Dn + r0 + tx] = f2bf(tile[tx][oc]);
    }
}

// ---- xsT[b][d][j] = bf16(xb[b][j][d] / s[b][j]); s computed in-kernel from partials ----
__global__ __launch_bounds__(256) void transpose_scale_bf16(
    const unsigned short* __restrict__ xb, unsigned short* __restrict__ out,
    const float* __restrict__ s_part, int nblk)
{
    __shared__ unsigned short tile[64][65];
    __shared__ float ss[64];
    const int z = blockIdx.z;
    const unsigned short* inb = xb + (size_t)z * Nn * Dn;
    unsigned short* ob = out + (size_t)z * Nn * Dn;
    const int j0 = blockIdx.y * 64, d0 = blockIdx.x * 64;
    const int tx = threadIdx.x & 63, ty = threadIdx.x >> 6;
    if (threadIdx.x < 64) {
        float acc = 0.f;
        for (int p = 0; p < nblk; ++p)
            acc += s_part[((size_t)z * nblk + p) * Nn + j0 + threadIdx.x];
        ss[threadIdx.x] = acc;
    }
#pragma unroll
    for (int p = 0; p < 64; p += 4) {
        const int r = p + ty;
        tile[r][tx] = inb[(size_t)(j0 + r) * Dn + d0 + tx];
    }
    __syncthreads();
    const float sv = ss[tx];
#pragma unroll
    for (int p = 0; p < 64; p += 4) {
        const int oc = p + ty;
        ob[(size_t)(d0 + oc) * Nn + j0 + tx] = f2bf(bf2f(tile[tx][oc]) / sv);
    }
}

// ===== 256x128 single-buffer 2-barrier GEMM, 4 waves, wave-tile 128x64 — PROJ shape =====
// (R10-proven winner for M=16384,N=1024,K=512.)
__global__ __launch_bounds__(256, 2) void gemw3(
    const unsigned short* __restrict__ A, int lda,
    const unsigned short* __restrict__ Bt, int ldb,
    unsigned short* __restrict__ Cp,
    const float* __restrict__ bias, const float* __restrict__ bias2, int bsplit,
    int M, int N, int K, int gx, int gy)
{
    __shared__ unsigned short As[256 * 64];   // 32 KB
    __shared__ unsigned short Bs[128 * 64];   // 16 KB

    const int lin = xcd_swizzle(blockIdx.x, gridDim.x);
    const int by = lin / gx;
    const int bx = lin - by * gx;

    const int i0 = by * 256, j0 = bx * 128;

    const int t = threadIdx.x;
    const int lane = t & 63;
    const int w = t >> 6;              // 0..3
    const int wm = w >> 1, wn = w & 1; // wave-tile 128 x 64
    const int l15 = lane & 15, g = lane >> 4;

    f32x4 acc[8][4];
    const f32x4 zero4 = {0.f, 0.f, 0.f, 0.f};
#pragma unroll
    for (int mf = 0; mf < 8; ++mf)
#pragma unroll
        for (int nf = 0; nf < 4; ++nf) acc[mf][nf] = zero4;

    const int lrow = lane >> 3;
    const int gch = (lane & 7) ^ lrow;   // pre-swizzled source chunk (involution)

    for (int kt = 0; kt < K; kt += 64) {
#pragma unroll
        for (int i = 0; i < 8; ++i) {
            const int r = w * 64 + i * 8 + lrow;
            gload_lds16(A + (size_t)(i0 + r) * lda + kt + gch * 8,
                        As + (w * 64 + i * 8) * 64);
        }
#pragma unroll
        for (int i = 0; i < 4; ++i) {
            const int r = w * 32 + i * 8 + lrow;
            gload_lds16(Bt + (size_t)(j0 + r) * ldb + kt + gch * 8,
                        Bs + (w * 32 + i * 8) * 64);
        }
        __syncthreads();
#pragma unroll
        for (int kk = 0; kk < 64; kk += 32) {
            const int sl0 = (kk >> 3) + g;
            bf16x8 af[8], bfr[4];
#pragma unroll
            for (int mf = 0; mf < 8; ++mf) {
                const int row = wm * 128 + mf * 16 + l15;
                af[mf] = *(const bf16x8*)(As + row * 64 + ((sl0 ^ (row & 7)) * 8));
            }
#pragma unroll
            for (int nf = 0; nf < 4; ++nf) {
                const int row = wn * 64 + nf * 16 + l15;
                bfr[nf] = *(const bf16x8*)(Bs + row * 64 + ((sl0 ^ (row & 7)) * 8));
            }
#pragma unroll
            for (int mf = 0; mf < 8; ++mf)
#pragma unroll
                for (int nf = 0; nf < 4; ++nf)
                    acc[mf][nf] = __builtin_amdgcn_mfma_f32_16x16x32_bf16(af[mf], bfr[nf], acc[mf][nf], 0, 0, 0);
        }
        __syncthreads();
    }

    const int col0 = j0 + wn * 64 + l15;
    float bv[4];
#pragma unroll
    for (int nf = 0; nf < 4; ++nf) {
        const int col = col0 + nf * 16;
        bv[nf] = (col < bsplit) ? bias[col] : bias2[col - bsplit];
    }
#pragma unroll
    for (int mf = 0; mf < 8; ++mf) {
        const int rb = i0 + wm * 128 + mf * 16 + g * 4;
#pragma unroll
        for (int r = 0; r < 4; ++r) {
            unsigned short* Crow = Cp + (size_t)(rb + r) * N + col0;
#pragma unroll
            for (int nf = 0; nf < 4; ++nf)
                Crow[nf * 16] = f2bf(acc[mf][nf][r] + bv[nf]);
        }
    }
}

// ======= 128x128 single-buffer 2-barrier GEMM (R8-proven best for energy & PV) =======
// MODE 1: C bf16=exp(acc) + col-sum partials | MODE 2: C f32
template<int MODE>
__global__ __launch_bounds__(256, 2) void gemm_bt(
    const unsigned short* __restrict__ A, long long sA, int lda,
    const unsigned short* __restrict__ Bt, long long sB, int ldb,
    void* __restrict__ Cp, long long sC,
    float* __restrict__ s_part,
    int M, int N, int K, int gx, int gy)
{
    __shared__ unsigned short As[128 * 64];
    __shared__ unsigned short Bs[128 * 64];
    __shared__ float s_red[256];

    const int lin = xcd_swizzle(blockIdx.x, gridDim.x);
    const int bz = lin / (gx * gy);
    const int rem = lin - bz * gx * gy;
    const int by = rem / gx;
    const int bx = rem - by * gx;

    const unsigned short* Ab = A + (size_t)bz * sA;
    const unsigned short* Bb = Bt + (size_t)bz * sB;
    const int i0 = by * 128, j0 = bx * 128;

    const int t = threadIdx.x;
    const int lane = t & 63;
    const int wave = t >> 6;
    const int wr = wave >> 1, wc = wave & 1;
    const int l15 = lane & 15, g = lane >> 4;

    f32x4 acc[4][4];
    const f32x4 zero4 = {0.f, 0.f, 0.f, 0.f};
#pragma unroll
    for (int mi = 0; mi < 4; ++mi)
#pragma unroll
        for (int ni = 0; ni < 4; ++ni) acc[mi][ni] = zero4;

    const int rbase = wave * 32;
    const int lrow = lane >> 3;
    const int gch = (lane & 7) ^ lrow;

    for (int kt = 0; kt < K; kt += 64) {
#pragma unroll
        for (int i = 0; i < 4; ++i) {
            const int r = rbase + i * 8 + lrow;
            gload_lds16(Ab + (size_t)(i0 + r) * lda + kt + gch * 8, As + (rbase + i * 8) * 64);
            gload_lds16(Bb + (size_t)(j0 + r) * ldb + kt + gch * 8, Bs + (rbase + i * 8) * 64);
        }
        __syncthreads();
#pragma unroll
        for (int kk = 0; kk < 64; kk += 32) {
            const int sl0 = (kk >> 3) + g;
            bf16x8 af[4], bfr[4];
#pragma unroll
            for (int mi = 0; mi < 4; ++mi) {
                const int row = wr * 64 + mi * 16 + l15;
                af[mi] = *(const bf16x8*)(As + row * 64 + ((sl0 ^ (row & 7)) * 8));
            }
#pragma unroll
            for (int ni = 0; ni < 4; ++ni) {
                const int row = wc * 64 + ni * 16 + l15;
                bfr[ni] = *(const bf16x8*)(Bs + row * 64 + ((sl0 ^ (row & 7)) * 8));
            }
#pragma unroll
            for (int mi = 0; mi < 4; ++mi)
#pragma unroll
                for (int ni = 0; ni < 4; ++ni)
                    acc[mi][ni] = __builtin_amdgcn_mfma_f32_16x16x32_bf16(af[mi], bfr[ni], acc[mi][ni], 0, 0, 0);
        }
        __syncthreads();
    }

    const int col0 = j0 + wc * 64 + l15;
    if (MODE == 1) {
        unsigned short* C = (unsigned short*)Cp + (size_t)bz * sC;
        float cs[4] = {0.f, 0.f, 0.f, 0.f};
#pragma unroll
        for (int mi = 0; mi < 4; ++mi) {
            const int rb = i0 + wr * 64 + mi * 16 + g * 4;
#pragma unroll
            for (int r = 0; r < 4; ++r) {
                unsigned short* Crow = C + (size_t)(rb + r) * N + col0;
#pragma unroll
                for (int ni = 0; ni < 4; ++ni) {
                    const float e = __expf(acc[mi][ni][r]);
                    const unsigned short h = f2bf(e);
                    Crow[ni * 16] = h;
                    cs[ni] += bf2f(h);   // sum rounded value: num/denom consistency
                }
            }
        }
#pragma unroll
        for (int ni = 0; ni < 4; ++ni) {
            cs[ni] += __shfl_xor(cs[ni], 16);
            cs[ni] += __shfl_xor(cs[ni], 32);
        }
        if (g == 0) {
#pragma unroll
            for (int ni = 0; ni < 4; ++ni)
                s_red[wr * 128 + wc * 64 + ni * 16 + l15] = cs[ni];
        }
        __syncthreads();
        if (t < 128) {
            const float sp = s_red[t] + s_red[128 + t];
            s_part[((size_t)bz * gy + by) * Nn + j0 + t] = sp;
        }
    } else {
        float* C = (float*)Cp + (size_t)bz * sC;
#pragma unroll
        for (int mi = 0; mi < 4; ++mi) {
            const int rb = i0 + wr * 64 + mi * 16 + g * 4;
#pragma unroll
            for (int r = 0; r < 4; ++r) {
                float* Crow = C + (size_t)(rb + r) * N + col0;
#pragma unroll
                for (int ni = 0; ni < 4; ++ni)
                    Crow[ni * 16] = acc[mi][ni][r];
            }
        }
    }
}

extern "C" void kernel_launch(void* const* d_in, const int* in_sizes, int n_in,
                              void* d_out, int out_size, void* d_ws, size_t ws_size,
                              hipStream_t stream) {
    const float* x  = (const float*)d_in[0];
    const float* Wq = (const float*)d_in[1];
    const float* bq = (const float*)d_in[2];
    const float* Wk = (const float*)d_in[3];
    const float* bk = (const float*)d_in[4];
    float* out = (float*)d_out;

    // ws layout (116 MB): xsT reuses qk's space (qk dead after energy GEMM)
    char* ws = (char*)d_ws;
    unsigned short* xb    = (unsigned short*)(ws);                               // 0..16 MB
    unsigned short* qk    = (unsigned short*)(ws + (16ull << 20));               // 16..48 MB [16384][1024]
    unsigned short* xsT   = (unsigned short*)(ws + (16ull << 20));               // reuse (written step 5)
    unsigned short* WqkT  = (unsigned short*)(ws + (48ull << 20));               // 48..49 MB [1024][512]
    float*          s_prt = (float*)(ws + (49ull << 20));                        // 49..51 MB
    unsigned short* expE  = (unsigned short*)(ws + (52ull << 20));               // 52..116 MB
    if (ws_size < (116ull << 20)) {
        fprintf(stderr, "WS TOO SMALL: have %zu need %llu\n", ws_size, (116ull << 20));
    }

    // 1) xb = bf16(x)
    cast_x_kernel<<<dim3((Bn * Nn * Dn) / (8 * 256)), 256, 0, stream>>>(x, xb, Bn * Nn * Dn);
    // 2) WqkT = bf16([Wq; Wk]^T)
    transpose_cast_w<<<dim3(Hn / 64, Dn / 64, 2), 256, 0, stream>>>(Wq, Wk, WqkT);
    // 3) qk = xb @ [Wq|Wk] + [bq|bk]   (M=16384, N=1024, K=512) — gemw3, 8 x 64 = 512 blocks
    {
        const int gx = (2 * Hn) / 128, gy = (Bn * Nn) / 256;
        gemw3<<<dim3(gx * gy), 256, 0, stream>>>(
            xb, Dn, WqkT, Dn, qk, bq, bk, Hn, Bn * Nn, 2 * Hn, Dn, gx, gy);
    }
    // 4) expE = exp(q @ k^T) + col-sum partials (per batch; M=N=2048, K=512) — 16x16x8 = 2048 blocks
    {
        const int gx = Nn / 128, gy = Nn / 128;
        gemm_bt<1><<<dim3(gx * gy * Bn), 256, 0, stream>>>(
            qk, (long long)Nn * 2 * Hn, 2 * Hn,               // q = qk[:, 0:512]
            qk + Hn, (long long)Nn * 2 * Hn, 2 * Hn,          // k = qk[:, 512:1024]
            expE, (long long)Nn * Nn, s_prt,
            Nn, Nn, Hn, gx, gy);
    }
    // 5) xsT[b][d][j] = bf16(xb[b][j][d] / s[b][j])  (s summed in-kernel from 16 partials)
    transpose_scale_bf16<<<dim3(Dn / 64, Nn / 64, Bn), 256, 0, stream>>>(xb, xsT, s_prt, Nn / 128);
    // 6) out = expE @ xsT^T   (per batch; M=2048, N=512, K=2048) — 4 x 16 x 8 = 512 blocks
    {
        const int gx = Dn / 128, gy = Nn / 128;
        gemm_bt<2><<<dim3(gx * gy * Bn), 256, 0, stream>>>(
            expE, (long long)Nn * Nn, Nn, xsT, (long long)Dn * Nn, Nn,
            out, (long long)Nn * Dn, nullptr,
            Nn, Dn, Nn, gx, gy);
    }
}

// Round 14
// 131.281 us; speedup vs baseline: 1.6448x; 1.0386x over previous
//
#include <hip/hip_runtime.h>
#include <hip/hip_bf16.h>
#include <cstdio>

typedef float f32x4 __attribute__((ext_vector_type(4)));
typedef __bf16 bf16x8 __attribute__((ext_vector_type(8)));

static constexpr int Bn = 8, Nn = 2048, Dn = 512, Hn = 512;

__device__ __forceinline__ unsigned short f2bf(float x) {
    union { float f; unsigned int u; } v; v.f = x;
    unsigned int r = (v.u + 0x7FFFu + ((v.u >> 16) & 1u)) >> 16;
    return (unsigned short)r;
}
__device__ __forceinline__ float bf2f(unsigned short h) {
    union { unsigned int u; float f; } v; v.u = ((unsigned int)h) << 16;
    return v.f;
}

__device__ __forceinline__ void gload_lds16(const unsigned short* g, unsigned short* l) {
    __builtin_amdgcn_global_load_lds(
        (const __attribute__((address_space(1))) void*)g,
        (__attribute__((address_space(3))) void*)l,
        16, 0, 0);
}

__device__ __forceinline__ int xcd_swizzle(int lin, int nwg) {
    return (lin & 7) * (nwg >> 3) + (lin >> 3);   // all grids %8==0
}

// ---------------- cast x (f32 -> bf16), flat ----------------
__global__ void cast_x_kernel(const float* __restrict__ x, unsigned short* __restrict__ xb, int n) {
    int i = (blockIdx.x * blockDim.x + threadIdx.x) * 8;
    if (i >= n) return;
    float4 a = *(const float4*)(x + i);
    float4 b = *(const float4*)(x + i + 4);
    unsigned short tmp[8] = {f2bf(a.x), f2bf(a.y), f2bf(a.z), f2bf(a.w),
                             f2bf(b.x), f2bf(b.y), f2bf(b.z), f2bf(b.w)};
    *(uint4*)(xb + i) = *(const uint4*)tmp;
}

// ---- weight transpose+cast: z=0 -> Wq, z=1 -> Wk; f32 [D][H] -> bf16 [H][D] ----
__global__ __launch_bounds__(256) void transpose_cast_w(
    const float* __restrict__ Wq, const float* __restrict__ Wk,
    unsigned short* __restrict__ out)
{
    __shared__ float tile[64][65];
    const int z = blockIdx.z;
    const float* inb = z ? Wk : Wq;
    unsigned short* outb = out + (size_t)z * Hn * Dn;
    const int r0 = blockIdx.y * 64, c0 = blockIdx.x * 64;
    const int tx = threadIdx.x & 63, ty = threadIdx.x >> 6;
#pragma unroll
    for (int p = 0; p < 64; p += 4) {
        const int r = p + ty;
        tile[r][tx] = inb[(size_t)(r0 + r) * Hn + c0 + tx];
    }
    __syncthreads();
#pragma unroll
    for (int p = 0; p < 64; p += 4) {
        const int oc = p + ty;
        outb[(size_t)(c0 + oc) * Dn + r0 + tx] = f2bf(tile[tx][oc]);
    }
}

// ---- xsT[b][d][j] = bf16(xb[b][j][d] / s[b][j]); s computed in-kernel from partials ----
__global__ __launch_bounds__(256) void transpose_scale_bf16(
    const unsigned short* __restrict__ xb, unsigned short* __restrict__ out,
    const float* __restrict__ s_part, int nblk)
{
    __shared__ unsigned short tile[64][65];
    __shared__ float ss[64];
    const int z = blockIdx.z;
    const unsigned short* inb = xb + (size_t)z * Nn * Dn;
    unsigned short* ob = out + (size_t)z * Nn * Dn;
    const int j0 = blockIdx.y * 64, d0 = blockIdx.x * 64;
    const int tx = threadIdx.x & 63, ty = threadIdx.x >> 6;
    if (threadIdx.x < 64) {
        float acc = 0.f;
        for (int p = 0; p < nblk; ++p)
            acc += s_part[((size_t)z * nblk + p) * Nn + j0 + threadIdx.x];
        ss[threadIdx.x] = acc;
    }
#pragma unroll
    for (int p = 0; p < 64; p += 4) {
        const int r = p + ty;
        tile[r][tx] = inb[(size_t)(j0 + r) * Dn + d0 + tx];
    }
    __syncthreads();
    const float sv = ss[tx];
#pragma unroll
    for (int p = 0; p < 64; p += 4) {
        const int oc = p + ty;
        ob[(size_t)(d0 + oc) * Nn + j0 + tx] = f2bf(bf2f(tile[tx][oc]) / sv);
    }
}

// ===== 256x128 single-buffer 2-barrier GEMM, 4 waves, wave-tile 128x64 (MF=8,NF=4) =====
// reads/MFMA = 1/8 + 1/4 = 0.375. R8-proven recipe: chunk^(row&7) involution on both
// stage-source and read side, gload_lds w16, stage->sync->compute->sync,
// nf-innermost epilogue stores. LDS 48KB + 1KB red; acc 128 VGPR.
// MODE 0: C bf16 + bias split | MODE 1: C bf16=exp(acc) + col-sum partials
template<int MODE>
__global__ __launch_bounds__(256, 2) void gemw3(
    const unsigned short* __restrict__ A, long long sA, int lda,
    const unsigned short* __restrict__ Bt, long long sB, int ldb,
    void* __restrict__ Cp, long long sC,
    const float* __restrict__ bias, const float* __restrict__ bias2, int bsplit,
    float* __restrict__ s_part,
    int M, int N, int K, int gx, int gy)
{
    __shared__ unsigned short As[256 * 64];   // 32 KB
    __shared__ unsigned short Bs[128 * 64];   // 16 KB
    __shared__ float s_red[2][128];           // 1 KB (MODE 1)

    const int lin = xcd_swizzle(blockIdx.x, gridDim.x);
    const int bz = lin / (gx * gy);
    const int rem = lin - bz * gx * gy;
    const int by = rem / gx;
    const int bx = rem - by * gx;

    const unsigned short* Ab = A + (size_t)bz * sA;
    const unsigned short* Bb = Bt + (size_t)bz * sB;
    const int i0 = by * 256, j0 = bx * 128;

    const int t = threadIdx.x;
    const int lane = t & 63;
    const int w = t >> 6;              // 0..3
    const int wm = w >> 1, wn = w & 1; // wave-tile 128 x 64
    const int l15 = lane & 15, g = lane >> 4;

    f32x4 acc[8][4];
    const f32x4 zero4 = {0.f, 0.f, 0.f, 0.f};
#pragma unroll
    for (int mf = 0; mf < 8; ++mf)
#pragma unroll
        for (int nf = 0; nf < 4; ++nf) acc[mf][nf] = zero4;

    const int lrow = lane >> 3;
    const int gch = (lane & 7) ^ lrow;   // pre-swizzled source chunk (involution)

    for (int kt = 0; kt < K; kt += 64) {
#pragma unroll
        for (int i = 0; i < 8; ++i) {
            const int r = w * 64 + i * 8 + lrow;
            gload_lds16(Ab + (size_t)(i0 + r) * lda + kt + gch * 8,
                        As + (w * 64 + i * 8) * 64);
        }
#pragma unroll
        for (int i = 0; i < 4; ++i) {
            const int r = w * 32 + i * 8 + lrow;
            gload_lds16(Bb + (size_t)(j0 + r) * ldb + kt + gch * 8,
                        Bs + (w * 32 + i * 8) * 64);
        }
        __syncthreads();
#pragma unroll
        for (int kk = 0; kk < 64; kk += 32) {
            const int sl0 = (kk >> 3) + g;
            bf16x8 af[8], bfr[4];
#pragma unroll
            for (int mf = 0; mf < 8; ++mf) {
                const int row = wm * 128 + mf * 16 + l15;
                af[mf] = *(const bf16x8*)(As + row * 64 + ((sl0 ^ (row & 7)) * 8));
            }
#pragma unroll
            for (int nf = 0; nf < 4; ++nf) {
                const int row = wn * 64 + nf * 16 + l15;
                bfr[nf] = *(const bf16x8*)(Bs + row * 64 + ((sl0 ^ (row & 7)) * 8));
            }
#pragma unroll
            for (int mf = 0; mf < 8; ++mf)
#pragma unroll
                for (int nf = 0; nf < 4; ++nf)
                    acc[mf][nf] = __builtin_amdgcn_mfma_f32_16x16x32_bf16(af[mf], bfr[nf], acc[mf][nf], 0, 0, 0);
        }
        __syncthreads();
    }

    const int col0 = j0 + wn * 64 + l15;
    if (MODE == 0) {
        unsigned short* C = (unsigned short*)Cp;
        float bv[4];
#pragma unroll
        for (int nf = 0; nf < 4; ++nf) {
            const int col = col0 + nf * 16;
            bv[nf] = (col < bsplit) ? bias[col] : bias2[col - bsplit];
        }
#pragma unroll
        for (int mf = 0; mf < 8; ++mf) {
            const int rb = i0 + wm * 128 + mf * 16 + g * 4;
#pragma unroll
            for (int r = 0; r < 4; ++r) {
                unsigned short* Crow = C + (size_t)(rb + r) * N + col0;
#pragma unroll
                for (int nf = 0; nf < 4; ++nf)
                    Crow[nf * 16] = f2bf(acc[mf][nf][r] + bv[nf]);
            }
        }
    } else {
        unsigned short* C = (unsigned short*)Cp + (size_t)bz * sC;
        float cs[4] = {0.f, 0.f, 0.f, 0.f};
#pragma unroll
        for (int mf = 0; mf < 8; ++mf) {
            const int rb = i0 + wm * 128 + mf * 16 + g * 4;
#pragma unroll
            for (int r = 0; r < 4; ++r) {
                unsigned short* Crow = C + (size_t)(rb + r) * N + col0;
#pragma unroll
                for (int nf = 0; nf < 4; ++nf) {
                    const float e = __expf(acc[mf][nf][r]);
                    const unsigned short h = f2bf(e);
                    Crow[nf * 16] = h;
                    cs[nf] += bf2f(h);   // sum rounded value: num/denom consistency
                }
            }
        }
#pragma unroll
        for (int nf = 0; nf < 4; ++nf) {
            cs[nf] += __shfl_xor(cs[nf], 16);
            cs[nf] += __shfl_xor(cs[nf], 32);
        }
        __syncthreads();
        if (g == 0) {
#pragma unroll
            for (int nf = 0; nf < 4; ++nf)
                s_red[wm][wn * 64 + nf * 16 + l15] = cs[nf];
        }
        __syncthreads();
        if (t < 128)
            s_part[((size_t)bz * gy + by) * Nn + j0 + t] = s_red[0][t] + s_red[1][t];
    }
}

// ======= 128x128 single-buffer 2-barrier GEMM (R8-proven) — PV only (f32 out) =======
__global__ __launch_bounds__(256, 2) void gemm_bt(
    const unsigned short* __restrict__ A, long long sA, int lda,
    const unsigned short* __restrict__ Bt, long long sB, int ldb,
    float* __restrict__ Cp, long long sC,
    int M, int N, int K, int gx, int gy)
{
    __shared__ unsigned short As[128 * 64];
    __shared__ unsigned short Bs[128 * 64];

    const int lin = xcd_swizzle(blockIdx.x, gridDim.x);
    const int bz = lin / (gx * gy);
    const int rem = lin - bz * gx * gy;
    const int by = rem / gx;
    const int bx = rem - by * gx;

    const unsigned short* Ab = A + (size_t)bz * sA;
    const unsigned short* Bb = Bt + (size_t)bz * sB;
    const int i0 = by * 128, j0 = bx * 128;

    const int t = threadIdx.x;
    const int lane = t & 63;
    const int wave = t >> 6;
    const int wr = wave >> 1, wc = wave & 1;
    const int l15 = lane & 15, g = lane >> 4;

    f32x4 acc[4][4];
    const f32x4 zero4 = {0.f, 0.f, 0.f, 0.f};
#pragma unroll
    for (int mi = 0; mi < 4; ++mi)
#pragma unroll
        for (int ni = 0; ni < 4; ++ni) acc[mi][ni] = zero4;

    const int rbase = wave * 32;
    const int lrow = lane >> 3;
    const int gch = (lane & 7) ^ lrow;

    for (int kt = 0; kt < K; kt += 64) {
#pragma unroll
        for (int i = 0; i < 4; ++i) {
            const int r = rbase + i * 8 + lrow;
            gload_lds16(Ab + (size_t)(i0 + r) * lda + kt + gch * 8, As + (rbase + i * 8) * 64);
            gload_lds16(Bb + (size_t)(j0 + r) * ldb + kt + gch * 8, Bs + (rbase + i * 8) * 64);
        }
        __syncthreads();
#pragma unroll
        for (int kk = 0; kk < 64; kk += 32) {
            const int sl0 = (kk >> 3) + g;
            bf16x8 af[4], bfr[4];
#pragma unroll
            for (int mi = 0; mi < 4; ++mi) {
                const int row = wr * 64 + mi * 16 + l15;
                af[mi] = *(const bf16x8*)(As + row * 64 + ((sl0 ^ (row & 7)) * 8));
            }
#pragma unroll
            for (int ni = 0; ni < 4; ++ni) {
                const int row = wc * 64 + ni * 16 + l15;
                bfr[ni] = *(const bf16x8*)(Bs + row * 64 + ((sl0 ^ (row & 7)) * 8));
            }
#pragma unroll
            for (int mi = 0; mi < 4; ++mi)
#pragma unroll
                for (int ni = 0; ni < 4; ++ni)
                    acc[mi][ni] = __builtin_amdgcn_mfma_f32_16x16x32_bf16(af[mi], bfr[ni], acc[mi][ni], 0, 0, 0);
        }
        __syncthreads();
    }

    float* C = Cp + (size_t)bz * sC;
    const int col0 = j0 + wc * 64 + l15;
#pragma unroll
    for (int mi = 0; mi < 4; ++mi) {
        const int rb = i0 + wr * 64 + mi * 16 + g * 4;
#pragma unroll
        for (int r = 0; r < 4; ++r) {
            float* Crow = C + (size_t)(rb + r) * N + col0;
#pragma unroll
            for (int ni = 0; ni < 4; ++ni)
                Crow[ni * 16] = acc[mi][ni][r];
        }
    }
}

extern "C" void kernel_launch(void* const* d_in, const int* in_sizes, int n_in,
                              void* d_out, int out_size, void* d_ws, size_t ws_size,
                              hipStream_t stream) {
    const float* x  = (const float*)d_in[0];
    const float* Wq = (const float*)d_in[1];
    const float* bq = (const float*)d_in[2];
    const float* Wk = (const float*)d_in[3];
    const float* bk = (const float*)d_in[4];
    float* out = (float*)d_out;

    // ws layout (116 MB): xsT reuses qk's space (qk dead after energy GEMM)
    char* ws = (char*)d_ws;
    unsigned short* xb    = (unsigned short*)(ws);                               // 0..16 MB
    unsigned short* qk    = (unsigned short*)(ws + (16ull << 20));               // 16..48 MB [16384][1024]
    unsigned short* xsT   = (unsigned short*)(ws + (16ull << 20));               // reuse (written step 5)
    unsigned short* WqkT  = (unsigned short*)(ws + (48ull << 20));               // 48..49 MB [1024][512]
    float*          s_prt = (float*)(ws + (49ull << 20));                        // 49..51 MB
    unsigned short* expE  = (unsigned short*)(ws + (52ull << 20));               // 52..116 MB
    if (ws_size < (116ull << 20)) {
        fprintf(stderr, "WS TOO SMALL: have %zu need %llu\n", ws_size, (116ull << 20));
    }

    // 1) xb = bf16(x)
    cast_x_kernel<<<dim3((Bn * Nn * Dn) / (8 * 256)), 256, 0, stream>>>(x, xb, Bn * Nn * Dn);
    // 2) WqkT = bf16([Wq; Wk]^T)
    transpose_cast_w<<<dim3(Hn / 64, Dn / 64, 2), 256, 0, stream>>>(Wq, Wk, WqkT);
    // 3) qk = xb @ [Wq|Wk] + [bq|bk]   (M=16384, N=1024, K=512) — 8 x 64 = 512 blocks
    {
        const int gx = (2 * Hn) / 128, gy = (Bn * Nn) / 256;
        gemw3<0><<<dim3(gx * gy), 256, 0, stream>>>(
            xb, 0, Dn, WqkT, 0, Dn, qk, 0, bq, bk, Hn, nullptr,
            Bn * Nn, 2 * Hn, Dn, gx, gy);
    }
    // 4) expE = exp(q @ k^T) + col-sum partials (per batch; M=N=2048, K=512) — 16x8x8 = 1024 blocks
    {
        const int gx = Nn / 128, gy = Nn / 256;
        gemw3<1><<<dim3(gx * gy * Bn), 256, 0, stream>>>(
            qk, (long long)Nn * 2 * Hn, 2 * Hn,               // q = qk[:, 0:512]
            qk + Hn, (long long)Nn * 2 * Hn, 2 * Hn,          // k = qk[:, 512:1024]
            expE, (long long)Nn * Nn, nullptr, nullptr, 0, s_prt,
            Nn, Nn, Hn, gx, gy);
    }
    // 5) xsT[b][d][j] = bf16(xb[b][j][d] / s[b][j])  (s summed in-kernel from 8 partials)
    transpose_scale_bf16<<<dim3(Dn / 64, Nn / 64, Bn), 256, 0, stream>>>(xb, xsT, s_prt, Nn / 256);
    // 6) out = expE @ xsT^T   (per batch; M=2048, N=512, K=2048) — 4 x 16 x 8 = 512 blocks
    {
        const int gx = Dn / 128, gy = Nn / 128;
        gemm_bt<<<dim3(gx * gy * Bn), 256, 0, stream>>>(
            expE, (long long)Nn * Nn, Nn, xsT, (long long)Dn * Nn, Nn,
            out, (long long)Nn * Dn, Nn, Dn, Nn, gx, gy);
    }
}